// Round 8
// baseline (105.414 us; speedup 1.0000x reference)
//
#include <hip/hip_runtime.h>
#include <hip/hip_bf16.h>
#include <stdint.h>

// ---------------------------------------------------------------------------
// coAttention: out = V_i + V_t + 0.5*V_c + 0.5*V_e
// V = softmax_n( sum_k tanh(feat@W)[n,k]*wp[K+k] + bias[n] ) @ feat.
// Query half of tanh-concat cancels in softmax -> 4 independent stages:
// c(N=20), e(30), i(49), t(128); B=256, D=1024, K=256.
// M = B*N: 5120/7680/12544/32768 -> 256-row tiles: 20/30/49/128 = 227 blocks.
//
// R7: byte-bound model (fits R2/R3/R4/R6): dur ~ total vector-load bytes
// at ~6.3 TB/s blended port rate, ANY source. B-traffic = 512KB * (M/BM).
// => maximize BM. BM=BN=256, 1024 thr (16 waves 4Mx4N, wave 64x64,
// acc=64 VGPR: the unique geometry fitting 4 waves/SIMD at <=128 VGPR).
// Logits bytes: A 233 + B 116 = 349 MB (R6 was 697). Ring-2 LDS A (bf16,
// XOR-swizzled), ONE barrier/body, A-prefetch issued at body top (compute
// body now ~4x longer -> latency actually hidden). B frag-native from L2.
// ---------------------------------------------------------------------------

#define D_DIM 1024
#define K_OUT 256
#define BM 256
#define BK 64
#define NT 16   // K-tiles = 1024/64

typedef float f32x4 __attribute__((ext_vector_type(4)));
typedef short bf16x8 __attribute__((ext_vector_type(8)));
typedef unsigned short u16x8 __attribute__((ext_vector_type(8)));

static __device__ __forceinline__ unsigned short f2bf(float f) {
    return __builtin_bit_cast(unsigned short, __float2bfloat16(f));
}

// tanh(x) = 1 - 2/(exp(2x)+1); stable at +/-inf.
static __device__ __forceinline__ float fast_tanh(float x) {
    float e = __expf(2.0f * x);
    return 1.0f - 2.0f / (e + 1.0f);
}

// ---------------------------------------------------------------------------
// Kernel 1: W (f32 [1024][256]) -> frag-native bf16:
// ushort off = kblk*4096 + col*16 + half*8 + j, where k = kblk*16+half*8+j.
// ---------------------------------------------------------------------------
__global__ __launch_bounds__(256) void convert_wt(
    const float* __restrict__ w_c, const float* __restrict__ w_e,
    const float* __restrict__ w_i, const float* __restrict__ w_t,
    unsigned short* __restrict__ wtf)
{
    const float* wsel[4] = {w_c, w_e, w_i, w_t};
    const float* W = wsel[blockIdx.x];
    unsigned short* out = wtf + (size_t)blockIdx.x * (K_OUT * D_DIM);
    const int kb = blockIdx.y;          // 0..63
    const int t = threadIdx.x;          // col 0..255

    unsigned short tmp[16];
#pragma unroll
    for (int j = 0; j < 16; ++j)
        tmp[j] = f2bf(W[(size_t)(kb * 16 + j) * K_OUT + t]);   // coalesced over t

    u16x8 lo, hi;
#pragma unroll
    for (int j = 0; j < 8; ++j) { lo[j] = tmp[j]; hi[j] = tmp[8 + j]; }
    unsigned short* dst = out + (size_t)kb * 4096 + t * 16;
    *reinterpret_cast<u16x8*>(dst) = lo;
    *reinterpret_cast<u16x8*>(dst + 8) = hi;
}

// ---------------------------------------------------------------------------
// Kernel 2: fused logits GEMM, BM=256 x 256 cols, BK=64, 1024 thr = 16 waves
// (4M x 4N, wave-tile 64x64: mt=4, nt=4). 32 MFMA/wave/body, 16 bodies.
// s[m] = sum_col tanh(proj[m,col]) * wp[256+col].
// ---------------------------------------------------------------------------
struct GemmStage {
    const float* feat;          // [M][1024] f32
    const unsigned short* wt;   // frag-native bf16, 256K ushorts
    const float* wp;            // [512] f32 (use [256..])
    float* s_out;               // [M]
    int blk_start;              // in 256-row tiles
};

__global__ __launch_bounds__(1024) void logits_gemm(
    GemmStage g0, GemmStage g1, GemmStage g2, GemmStage g3)
{
    __shared__ __align__(16) unsigned char As[2][BM * 128];  // 2 x 32 KB bf16
    __shared__ float partial[BM][16];                        // 16 KB

    const int bid = blockIdx.x;
    GemmStage st;
    if (bid < g1.blk_start) st = g0;
    else if (bid < g2.blk_start) st = g1;
    else if (bid < g3.blk_start) st = g2;
    else st = g3;
    const int m0 = (bid - st.blk_start) * BM;

    const int t = threadIdx.x;
    const int wv = t >> 6, lane = t & 63;
    const int wm = wv >> 2, wn = wv & 3;
    const int q = lane >> 4, c16 = lane & 15;

    // ---- A staging: thread -> (row r = t>>2, seg = t&3: 16 f32) ----
    const int r = t >> 2, seg = t & 3;
    const float* aptr = st.feat + (size_t)(m0 + r) * D_DIM + seg * 16;
    const int wo0 = r * 128 + (((seg * 2    ) ^ (r & 7)) << 4);
    const int wo1 = r * 128 + (((seg * 2 + 1) ^ (r & 7)) << 4);

    // ---- ds_read offsets: row = wm*64 + mt*16 + c16, chunk (ks*4+q)^(row&7) ----
    int rofs[4][2];
#pragma unroll
    for (int mt = 0; mt < 4; ++mt)
#pragma unroll
        for (int ks = 0; ks < 2; ++ks)
            rofs[mt][ks] = (wm * 64 + mt * 16 + c16) * 128
                         + ((((ks * 4 + q)) ^ (c16 & 7)) << 4);

    // ---- B frag-native: col = wn*64 + nt*16 + c16; k = kt*64 + ks*32 + q*8 ----
    const unsigned short* bb = st.wt + (size_t)(q >> 1) * 4096
                             + ((wn * 64 + c16) << 4) + (q & 1) * 8;

    float wpf[4];
#pragma unroll
    for (int nt = 0; nt < 4; ++nt) wpf[nt] = st.wp[K_OUT + wn * 64 + nt * 16 + c16];

    f32x4 acc[4][4];
#pragma unroll
    for (int i = 0; i < 4; ++i)
#pragma unroll
        for (int j = 0; j < 4; ++j) acc[i][j] = (f32x4){0.f, 0.f, 0.f, 0.f};

    f32x4 pa0, pa1, pa2, pa3;

    // ---- prologue: A(0) -> As[0] ----
    pa0 = *reinterpret_cast<const f32x4*>(aptr);
    pa1 = *reinterpret_cast<const f32x4*>(aptr + 4);
    pa2 = *reinterpret_cast<const f32x4*>(aptr + 8);
    pa3 = *reinterpret_cast<const f32x4*>(aptr + 12);
    {
        u16x8 o0, o1;
#pragma unroll
        for (int j = 0; j < 4; ++j) {
            o0[j] = f2bf(pa0[j]); o0[4 + j] = f2bf(pa1[j]);
            o1[j] = f2bf(pa2[j]); o1[4 + j] = f2bf(pa3[j]);
        }
        *reinterpret_cast<u16x8*>(&As[0][wo0]) = o0;
        *reinterpret_cast<u16x8*>(&As[0][wo1]) = o1;
    }
    __syncthreads();

#pragma unroll 1
    for (int kt = 0; kt < NT; ++kt) {
        const int cur = kt & 1;
        // ---- issue next tile's A loads (hidden under this body's compute) ----
        if (kt + 1 < NT) {
            const float* ap = aptr + (kt + 1) * BK;
            pa0 = *reinterpret_cast<const f32x4*>(ap);
            pa1 = *reinterpret_cast<const f32x4*>(ap + 4);
            pa2 = *reinterpret_cast<const f32x4*>(ap + 8);
            pa3 = *reinterpret_cast<const f32x4*>(ap + 12);
        }
        // ---- compute from As[cur]; B loaded per-ks from L2 ----
        const unsigned char* buf = As[cur];
        const unsigned short* bk = bb + (size_t)kt * 16384;
#pragma unroll
        for (int ks = 0; ks < 2; ++ks) {
            u16x8 bfr[4];
#pragma unroll
            for (int nt = 0; nt < 4; ++nt)
                bfr[nt] = *reinterpret_cast<const u16x8*>(bk + ks * 8192 + nt * 256);
            bf16x8 af[4];
#pragma unroll
            for (int mt = 0; mt < 4; ++mt)
                af[mt] = *reinterpret_cast<const bf16x8*>(&buf[rofs[mt][ks]]);
#pragma unroll
            for (int mt = 0; mt < 4; ++mt)
#pragma unroll
                for (int nt = 0; nt < 4; ++nt)
                    acc[mt][nt] = __builtin_amdgcn_mfma_f32_16x16x32_bf16(
                        af[mt], __builtin_bit_cast(bf16x8, bfr[nt]),
                        acc[mt][nt], 0, 0, 0);
        }
        // ---- convert + write next tile into the other buffer ----
        if (kt + 1 < NT) {
            u16x8 o0, o1;
#pragma unroll
            for (int j = 0; j < 4; ++j) {
                o0[j] = f2bf(pa0[j]); o0[4 + j] = f2bf(pa1[j]);
                o1[j] = f2bf(pa2[j]); o1[4 + j] = f2bf(pa3[j]);
            }
            unsigned char* nbuf = As[cur ^ 1];
            *reinterpret_cast<u16x8*>(&nbuf[wo0]) = o0;
            *reinterpret_cast<u16x8*>(&nbuf[wo1]) = o1;
        }
        __syncthreads();
    }

    // ---- epilogue: tanh * wp2, reduce cols -> s_out ----
    // C/D 16x16: col = c16 (+wn*64+nt*16), row = q*4 + rg (+wm*64+mt*16)
#pragma unroll
    for (int mt = 0; mt < 4; ++mt) {
#pragma unroll
        for (int rg = 0; rg < 4; ++rg) {
            float v = 0.f;
#pragma unroll
            for (int nt = 0; nt < 4; ++nt)
                v += fast_tanh(acc[mt][nt][rg]) * wpf[nt];
            v += __shfl_xor(v, 1);
            v += __shfl_xor(v, 2);
            v += __shfl_xor(v, 4);
            v += __shfl_xor(v, 8);
            if (c16 == 0) partial[wm * 64 + mt * 16 + q * 4 + rg][wn * 4 + (wv & 0)] = v;
            // NOTE: column index must be unique per wn; wv&0 ==0 -> use wn
        }
    }
    // fix: the line above writes [row][wn*4] -- but only 4 N-waves exist per row
    __syncthreads();
    if (t < BM) {
        float v = 0.f;
#pragma unroll
        for (int w = 0; w < 4; ++w) v += partial[t][w * 4];
        st.s_out[m0 + t] = v;
    }
}

// ---------------------------------------------------------------------------
// Kernel 3: per (b, stage): softmax over N logits (+bias), then V = P @ feat.
// ---------------------------------------------------------------------------
struct PVStage {
    const float* s;       // [B*N]
    const float* bias;    // [N]
    const float* feat;    // [B*N][1024]
    float* v_out;         // [B][1024]
    int N;
};

__global__ __launch_bounds__(256) void softmax_pv(
    PVStage p0, PVStage p1, PVStage p2, PVStage p3)
{
    PVStage st = (blockIdx.y == 0) ? p0 : (blockIdx.y == 1) ? p1
               : (blockIdx.y == 2) ? p2 : p3;
    const int b = blockIdx.x, t = threadIdx.x;
    const int N = st.N;

    __shared__ float P[128];
    __shared__ float inv_s;

    if (t < N) P[t] = st.s[b * N + t] + st.bias[t];
    __syncthreads();
    if (t < 64) {
        float m = -3.4e38f;
        for (int n = t; n < N; n += 64) m = fmaxf(m, P[n]);
#pragma unroll
        for (int sh = 32; sh; sh >>= 1) m = fmaxf(m, __shfl_xor(m, sh));
        float ssum = 0.f;
        for (int n = t; n < N; n += 64) { float e = __expf(P[n] - m); P[n] = e; ssum += e; }
#pragma unroll
        for (int sh = 32; sh; sh >>= 1) ssum += __shfl_xor(ssum, sh);
        if (t == 0) inv_s = 1.0f / ssum;
    }
    __syncthreads();
    const float inv = inv_s;

    f32x4 accv = (f32x4){0.f, 0.f, 0.f, 0.f};
    const float* fb = st.feat + (size_t)b * N * D_DIM + t * 4;
    for (int n = 0; n < N; ++n) {
        f32x4 f = *reinterpret_cast<const f32x4*>(fb + (size_t)n * D_DIM);
        accv += (P[n] * inv) * f;
    }
    *reinterpret_cast<f32x4*>(&st.v_out[(size_t)b * D_DIM + t * 4]) = accv;
}

// ---------------------------------------------------------------------------
// Kernel 4: out = V_i + V_t + 0.5*V_c + 0.5*V_e
// ---------------------------------------------------------------------------
__global__ __launch_bounds__(256) void combine_out(
    const float* __restrict__ vc, const float* __restrict__ ve,
    const float* __restrict__ vi, const float* __restrict__ vt,
    float* __restrict__ out)
{
    const int i = (blockIdx.x * 256 + threadIdx.x) * 4;
    f32x4 a = *reinterpret_cast<const f32x4*>(vi + i);
    f32x4 bb = *reinterpret_cast<const f32x4*>(vt + i);
    f32x4 c = *reinterpret_cast<const f32x4*>(vc + i);
    f32x4 e = *reinterpret_cast<const f32x4*>(ve + i);
    *reinterpret_cast<f32x4*>(out + i) = a + bb + 0.5f * c + 0.5f * e;
}

// ---------------------------------------------------------------------------
extern "C" void kernel_launch(void* const* d_in, const int* in_sizes, int n_in,
                              void* d_out, int out_size, void* d_ws, size_t ws_size,
                              hipStream_t stream)
{
    const float* ifeature = (const float*)d_in[0];   // (256,49,1024)
    const float* tfeature = (const float*)d_in[1];   // (256,128,1024)
    const float* cfeature = (const float*)d_in[2];   // (256,20,1024)
    const float* efeature = (const float*)d_in[3];   // (256,30,1024)
    const float* w_Vc = (const float*)d_in[5];
    const float* w_Pc = (const float*)d_in[6];
    const float* b_Pc = (const float*)d_in[7];
    const float* w_Ve = (const float*)d_in[8];
    const float* w_Pe = (const float*)d_in[9];
    const float* b_Pe = (const float*)d_in[10];
    const float* w_Vi = (const float*)d_in[11];
    const float* w_Pi = (const float*)d_in[13];
    const float* b_Pi = (const float*)d_in[14];
    const float* w_Vt = (const float*)d_in[16];
    const float* w_Pt = (const float*)d_in[17];
    const float* b_Pt = (const float*)d_in[18];

    // workspace layout (~7 MB)
    char* ws = (char*)d_ws;
    unsigned short* wtf = (unsigned short*)ws;                // 4 x 512KB bf16
    float* s_c = (float*)(ws + 2u * 1024 * 1024);             // 5120
    float* s_e = s_c + 5120;                                  // 7680
    float* s_i = s_e + 7680;                                  // 12544
    float* s_t = s_i + 12544;                                 // 32768
    float* v_c = (float*)(ws + 3u * 1024 * 1024);             // 4 x 1MB
    float* v_e = v_c + 256 * 1024;
    float* v_i = v_e + 256 * 1024;
    float* v_t = v_i + 256 * 1024;

    convert_wt<<<dim3(4, 64), 256, 0, stream>>>(w_Vc, w_Ve, w_Vi, w_Vt, wtf);

    // 256-row tiles: c=20, e=30, i=49, t=128 -> 227 blocks
    GemmStage g0{cfeature, wtf,          w_Pc, s_c, 0};
    GemmStage g1{efeature, wtf + 262144, w_Pe, s_e, 20};
    GemmStage g2{ifeature, wtf + 524288, w_Pi, s_i, 50};
    GemmStage g3{tfeature, wtf + 786432, w_Pt, s_t, 99};
    logits_gemm<<<227, 1024, 0, stream>>>(g0, g1, g2, g3);

    PVStage p0{s_c, b_Pc, cfeature, v_c, 20};
    PVStage p1{s_e, b_Pe, efeature, v_e, 30};
    PVStage p2{s_i, b_Pi, ifeature, v_i, 49};
    PVStage p3{s_t, b_Pt, tfeature, v_t, 128};
    softmax_pv<<<dim3(256, 4), 256, 0, stream>>>(p0, p1, p2, p3);

    combine_out<<<256, 256, 0, stream>>>(v_c, v_e, v_i, v_t, (float*)d_out);
}